// Round 12
// baseline (221.364 us; speedup 1.0000x reference)
//
#include <hip/hip_runtime.h>
#include <math.h>

#define BATCH 128
#define CIN 3
#define H 224
#define W 224
#define C1 16
#define HP 56
#define WP 56
#define C2 32
#define H2 28
#define W2 28

// bf16 pack/unpack: mm cell = (bf16(mx) << 16) | bf16(mn), RNE rounding.
__device__ __forceinline__ unsigned bf16r(float f) {
    const unsigned u = __float_as_uint(f);
    return (u + 0x7FFFu + ((u >> 16) & 1u)) >> 16;
}
__device__ __forceinline__ float bfhi(unsigned u) {   // mx
    return __uint_as_float(u & 0xFFFF0000u);
}
__device__ __forceinline__ float bflo(unsigned u) {   // mn
    return __uint_as_float(u << 16);
}

// ---------------------------------------------------------------------------
// conv1 (s2,p1) + stats + 2x2 pool(max,min), SINGLE PASS (R8-proven core).
// Thread = 2 vertically-adjacent pooled cells x 8 channels. Grid (784, 2).
// Epilogue change vs R8: pooled (max,min) packed to one uint (bf16x2) —
// halves WRITE (50 -> 25 MB). Stats remain fp32 from the fp32 accumulators.
// ---------------------------------------------------------------------------
__global__ __launch_bounds__(256) void conv1_fused_k(
    const float* __restrict__ x, const float* __restrict__ w1,
    const float* __restrict__ b1, unsigned* __restrict__ mmb,
    float* __restrict__ s_sum, float* __restrict__ s_sq)
{
    __shared__ float red[4][8], redq[4][8];
    const int tid = threadIdx.x;
    const int t = blockIdx.x * 256 + tid;   // 0..200703
    const int c0 = blockIdx.y * 8;
    const int n = t / 1568;
    const int r = t % 1568;
    const int phh = r / 56;                 // 0..27
    const int pw  = r % 56;
    const int rbase = 8 * phh - 1;
    const int cbase = 4 * pw;
    const bool topok = phh > 0;
    const bool pwok  = pw > 0;

    float accA[8][4], accB[8][4];
#pragma unroll
    for (int j = 0; j < 8; ++j) {
        const float bb = b1[c0 + j];
#pragma unroll
        for (int q = 0; q < 4; ++q) { accA[j][q] = bb; accB[j][q] = bb; }
    }

#pragma unroll
    for (int ci = 0; ci < CIN; ++ci) {
        const float* img = x + (n * CIN + ci) * (H * W);
        float p[9][5];
#pragma unroll
        for (int l = 0; l < 9; ++l) {
            const int ih = max(rbase + l, 0);
            const float* rowp = img + ih * W;
            const float4 f4 = *(const float4*)(rowp + cbase);
            const float lf = rowp[max(cbase - 1, 0)];
            const bool rok = (l > 0) || topok;   // folds for l>0
            p[l][0] = (rok && pwok) ? lf : 0.0f;
            p[l][1] = rok ? f4.x : 0.0f;
            p[l][2] = rok ? f4.y : 0.0f;
            p[l][3] = rok ? f4.z : 0.0f;
            p[l][4] = rok ? f4.w : 0.0f;
        }
#pragma unroll
        for (int j = 0; j < 8; ++j) {
            const float* wc = w1 + ((c0 + j) * CIN + ci) * 9;  // uniform
#pragma unroll
            for (int kh = 0; kh < 3; ++kh) {
#pragma unroll
                for (int kw = 0; kw < 3; ++kw) {
                    const float wv = wc[kh * 3 + kw];
                    accA[j][0] += wv * p[kh][kw];
                    accA[j][1] += wv * p[kh][kw + 2];
                    accA[j][2] += wv * p[kh + 2][kw];
                    accA[j][3] += wv * p[kh + 2][kw + 2];
                    accB[j][0] += wv * p[4 + kh][kw];
                    accB[j][1] += wv * p[4 + kh][kw + 2];
                    accB[j][2] += wv * p[6 + kh][kw];
                    accB[j][3] += wv * p[6 + kh][kw + 2];
                }
            }
        }
    }

#pragma unroll
    for (int j = 0; j < 8; ++j) {
        const int o = (n * C1 + c0 + j) * (HP * WP) + (2 * phh) * WP + pw;
        const float a0 = accA[j][0], a1 = accA[j][1], a2 = accA[j][2], a3 = accA[j][3];
        const float b0 = accB[j][0], b1v = accB[j][1], b2v = accB[j][2], b3 = accB[j][3];
        const float mxA = fmaxf(fmaxf(a0, a1), fmaxf(a2, a3));
        const float mnA = fminf(fminf(a0, a1), fminf(a2, a3));
        const float mxB = fmaxf(fmaxf(b0, b1v), fmaxf(b2v, b3));
        const float mnB = fminf(fminf(b0, b1v), fminf(b2v, b3));
        mmb[o]      = (bf16r(mxA) << 16) | bf16r(mnA);
        mmb[o + WP] = (bf16r(mxB) << 16) | bf16r(mnB);
        float s = a0 + a1 + a2 + a3 + b0 + b1v + b2v + b3;
        float q = a0 * a0 + a1 * a1 + a2 * a2 + a3 * a3
                + b0 * b0 + b1v * b1v + b2v * b2v + b3 * b3;
#pragma unroll
        for (int off = 32; off > 0; off >>= 1) {
            s += __shfl_xor(s, off);
            q += __shfl_xor(q, off);
        }
        if ((tid & 63) == 0) { red[tid >> 6][j] = s; redq[tid >> 6][j] = q; }
    }
    __syncthreads();
    if (tid < 8) {
        atomicAdd(&s_sum[c0 + tid],
                  red[0][tid] + red[1][tid] + red[2][tid] + red[3][tid]);
    } else if (tid < 16) {
        const int j = tid - 8;
        atomicAdd(&s_sq[c0 + j],
                  redq[0][j] + redq[1][j] + redq[2][j] + redq[3][j]);
    }
}

// ---------------------------------------------------------------------------
// conv2 (s2,p1) + stats; BN1 finalize folded in (R8-proven core).
// Thread = ONE output position x 8 channels. Grid (392, 4).
// Staging change vs R8: mm cells are packed bf16x2 uints — uint2 load at
// col 2*ow (8B-aligned) + scalar uint at 2*ow-1; 2-op unpack per value.
// ---------------------------------------------------------------------------
__global__ __launch_bounds__(256) void conv2_k(
    const unsigned* __restrict__ mmb,
    const float* __restrict__ s1sum, const float* __restrict__ s1sq,
    const float* __restrict__ g1, const float* __restrict__ be1,
    const float* __restrict__ w2, const float* __restrict__ b2,
    float* __restrict__ y2,
    float* __restrict__ s_sum, float* __restrict__ s_sq)
{
    __shared__ float red[4][8], redq[4][8];
    const int tid = threadIdx.x;
    const int t = blockIdx.x * 256 + tid;   // 0..100351
    const int c0 = blockIdx.y * 8;
    const int n = t / 784;
    const int p = t % 784;
    const int oh = p / W2, ow = p % W2;
    const bool topok = oh > 0;
    const bool owok  = ow > 0;
    const float inv1 = 1.0f / (float)(BATCH * 112 * 112);

    float acc[8];
#pragma unroll
    for (int c = 0; c < 8; ++c) acc[c] = b2[c0 + c];

#pragma unroll 2
    for (int ci = 0; ci < C1; ++ci) {
        const float mean = s1sum[ci] * inv1;
        const float var  = s1sq[ci] * inv1 - mean * mean;
        const float s1 = g1[ci] * rsqrtf(var + 1e-5f);
        const float t1 = be1[ci] - mean * s1;

        const unsigned* pl = mmb + (n * C1 + ci) * (HP * WP);
        float v[3][3];
#pragma unroll
        for (int kh = 0; kh < 3; ++kh) {
            const int ih = max(2 * oh - 1 + kh, 0);
            const unsigned* rowp = pl + ih * WP;
            const uint2 u2 = *(const uint2*)(rowp + 2 * ow);   // 8B-aligned
            const unsigned ul = rowp[max(2 * ow - 1, 0)];
            const bool rok = (kh > 0) || topok;   // folds for kh>0
            const float h0 = fmaxf(0.0f, fmaxf(s1 * bfhi(ul) + t1, s1 * bflo(ul) + t1));
            const float h1 = fmaxf(0.0f, fmaxf(s1 * bfhi(u2.x) + t1, s1 * bflo(u2.x) + t1));
            const float h2 = fmaxf(0.0f, fmaxf(s1 * bfhi(u2.y) + t1, s1 * bflo(u2.y) + t1));
            v[kh][0] = (rok && owok) ? h0 : 0.0f;
            v[kh][1] = rok ? h1 : 0.0f;
            v[kh][2] = rok ? h2 : 0.0f;
        }
#pragma unroll
        for (int c = 0; c < 8; ++c) {
            const float* wc = w2 + ((c0 + c) * C1 + ci) * 9;   // uniform
            float a = acc[c];
            a += wc[0] * v[0][0]; a += wc[1] * v[0][1]; a += wc[2] * v[0][2];
            a += wc[3] * v[1][0]; a += wc[4] * v[1][1]; a += wc[5] * v[1][2];
            a += wc[6] * v[2][0]; a += wc[7] * v[2][1]; a += wc[8] * v[2][2];
            acc[c] = a;
        }
    }

#pragma unroll
    for (int c = 0; c < 8; ++c) {
        const float a = acc[c];
        y2[(n * C2 + c0 + c) * (H2 * W2) + p] = a;
        float s = a, q = a * a;
#pragma unroll
        for (int off = 32; off > 0; off >>= 1) {
            s += __shfl_xor(s, off);
            q += __shfl_xor(q, off);
        }
        if ((tid & 63) == 0) { red[tid >> 6][c] = s; redq[tid >> 6][c] = q; }
    }
    __syncthreads();
    if (tid < 8) {
        atomicAdd(&s_sum[c0 + tid],
                  red[0][tid] + red[1][tid] + red[2][tid] + red[3][tid]);
    } else if (tid < 16) {
        const int c = tid - 8;
        atomicAdd(&s_sq[c0 + c],
                  redq[0][c] + redq[1][c] + redq[2][c] + redq[3][c]);
    }
}

// ---------------------------------------------------------------------------
// head fused: BN2 finalize + ReLU + avgpool + FC + cos, one block per image.
// (R8-proven, VERBATIM.)
// ---------------------------------------------------------------------------
__global__ __launch_bounds__(256) void head_fused_k(
    const float* __restrict__ y2,
    const float* __restrict__ s2sum, const float* __restrict__ s2sq,
    const float* __restrict__ g2, const float* __restrict__ be2,
    const float* __restrict__ fcw, const float* __restrict__ fcb,
    float* __restrict__ out)
{
    __shared__ float feat[C2];
    const int n = blockIdx.x;
    const int tid = threadIdx.x;
    const int wave = tid >> 6, lane = tid & 63;
    const float inv2 = 1.0f / (float)(BATCH * H2 * W2);
#pragma unroll
    for (int k = 0; k < 8; ++k) {
        const int c = wave * 8 + k;
        const float mean = s2sum[c] * inv2;
        const float var  = s2sq[c] * inv2 - mean * mean;
        const float s = g2[c] * rsqrtf(var + 1e-5f);
        const float t = be2[c] - mean * s;
        const float4* yp = (const float4*)(y2 + (n * C2 + c) * (H2 * W2));
        float a = 0.0f;
        for (int i = lane; i < 196; i += 64) {       // 196 quads = 784
            const float4 v = yp[i];
            a += fmaxf(0.0f, s * v.x + t) + fmaxf(0.0f, s * v.y + t)
               + fmaxf(0.0f, s * v.z + t) + fmaxf(0.0f, s * v.w + t);
        }
#pragma unroll
        for (int off = 32; off > 0; off >>= 1) a += __shfl_xor(a, off);
        if (lane == 0) feat[c] = a * (1.0f / (H2 * W2));
    }
    __syncthreads();
    if (tid == 0) {
        float logit = fcb[0];
#pragma unroll
        for (int c = 0; c < C2; ++c) logit += feat[c] * fcw[c];
        const float pc = cosf(logit);
        out[2 * n]     = pc;
        out[2 * n + 1] = 1.0f - pc;
    }
}

extern "C" void kernel_launch(void* const* d_in, const int* in_sizes, int n_in,
                              void* d_out, int out_size, void* d_ws, size_t ws_size,
                              hipStream_t stream) {
    const float* x   = (const float*)d_in[0];
    const float* w1  = (const float*)d_in[1];
    const float* b1  = (const float*)d_in[2];
    const float* g1  = (const float*)d_in[3];
    const float* be1 = (const float*)d_in[4];
    const float* w2  = (const float*)d_in[5];
    const float* b2  = (const float*)d_in[6];
    const float* g2  = (const float*)d_in[7];
    const float* be2 = (const float*)d_in[8];
    const float* fcw = (const float*)d_in[9];
    const float* fcb = (const float*)d_in[10];
    float* out = (float*)d_out;

    float* ws = (float*)d_ws;
    unsigned* mmb = (unsigned*)ws;                         // 6,422,528 uints (25.7 MB)
    float* y2 = ws + (size_t)BATCH * C1 * HP * WP;         // 3,211,264 floats
    float* stats = y2 + (size_t)BATCH * C2 * H2 * W2;
    float* s1sum = stats;          // 16
    float* s1sq  = stats + 16;     // 16
    float* s2sum = stats + 32;     // 32
    float* s2sq  = stats + 64;     // 32
    // ws use ~38.6 MB

    hipMemsetAsync(stats, 0, 96 * sizeof(float), stream);

    conv1_fused_k<<<dim3(784, 2), 256, 0, stream>>>(x, w1, b1, mmb, s1sum, s1sq);
    conv2_k<<<dim3(392, 4), 256, 0, stream>>>(mmb, s1sum, s1sq, g1, be1,
                                              w2, b2, y2, s2sum, s2sq);
    head_fused_k<<<BATCH, 256, 0, stream>>>(y2, s2sum, s2sq, g2, be2,
                                            fcw, fcb, out);
}

// Round 13
// 215.684 us; speedup vs baseline: 1.0263x; 1.0263x over previous
//
#include <hip/hip_runtime.h>
#include <math.h>

#define BATCH 128
#define CIN 3
#define H 224
#define W 224
#define C1 16
#define HP 56
#define WP 56
#define C2 32
#define H2 28
#define W2 28

// ---------------------------------------------------------------------------
// R8 configuration — empirical optimum over 12 rounds (214.95 us).
// conv1: 2 vertical pooled cells x 8 ch/thread, fp32 (max,min) float2 out.
// conv2: 1 position x 8 ch/thread, BN1 folded, grid (392,4).
// head: one block/image, BN2 folded, float4 reads, cos epilogue.
// Levers falsified: LDS tiling (R2/R3), more reuse/thread (R5/R10),
// SW pipelining (R9), packed FMA (R11), bf16 intermediate (R12),
// cooperative fusion (R7 — harness rejects). Occupancy is the only axis
// that ever won and it is saturated here.
// ---------------------------------------------------------------------------
__global__ __launch_bounds__(256) void conv1_fused_k(
    const float* __restrict__ x, const float* __restrict__ w1,
    const float* __restrict__ b1, float2* __restrict__ mm,
    float* __restrict__ s_sum, float* __restrict__ s_sq)
{
    __shared__ float red[4][8], redq[4][8];
    const int tid = threadIdx.x;
    const int t = blockIdx.x * 256 + tid;   // 0..200703
    const int c0 = blockIdx.y * 8;
    const int n = t / 1568;
    const int r = t % 1568;
    const int phh = r / 56;                 // 0..27
    const int pw  = r % 56;
    const int rbase = 8 * phh - 1;
    const int cbase = 4 * pw;
    const bool topok = phh > 0;
    const bool pwok  = pw > 0;

    float accA[8][4], accB[8][4];
#pragma unroll
    for (int j = 0; j < 8; ++j) {
        const float bb = b1[c0 + j];
#pragma unroll
        for (int q = 0; q < 4; ++q) { accA[j][q] = bb; accB[j][q] = bb; }
    }

#pragma unroll
    for (int ci = 0; ci < CIN; ++ci) {
        const float* img = x + (n * CIN + ci) * (H * W);
        float p[9][5];
#pragma unroll
        for (int l = 0; l < 9; ++l) {
            const int ih = max(rbase + l, 0);
            const float* rowp = img + ih * W;
            const float4 f4 = *(const float4*)(rowp + cbase);
            const float lf = rowp[max(cbase - 1, 0)];
            const bool rok = (l > 0) || topok;   // folds for l>0
            p[l][0] = (rok && pwok) ? lf : 0.0f;
            p[l][1] = rok ? f4.x : 0.0f;
            p[l][2] = rok ? f4.y : 0.0f;
            p[l][3] = rok ? f4.z : 0.0f;
            p[l][4] = rok ? f4.w : 0.0f;
        }
#pragma unroll
        for (int j = 0; j < 8; ++j) {
            const float* wc = w1 + ((c0 + j) * CIN + ci) * 9;  // uniform
#pragma unroll
            for (int kh = 0; kh < 3; ++kh) {
#pragma unroll
                for (int kw = 0; kw < 3; ++kw) {
                    const float wv = wc[kh * 3 + kw];
                    accA[j][0] += wv * p[kh][kw];
                    accA[j][1] += wv * p[kh][kw + 2];
                    accA[j][2] += wv * p[kh + 2][kw];
                    accA[j][3] += wv * p[kh + 2][kw + 2];
                    accB[j][0] += wv * p[4 + kh][kw];
                    accB[j][1] += wv * p[4 + kh][kw + 2];
                    accB[j][2] += wv * p[6 + kh][kw];
                    accB[j][3] += wv * p[6 + kh][kw + 2];
                }
            }
        }
    }

#pragma unroll
    for (int j = 0; j < 8; ++j) {
        const int o = (n * C1 + c0 + j) * (HP * WP) + (2 * phh) * WP + pw;
        const float a0 = accA[j][0], a1 = accA[j][1], a2 = accA[j][2], a3 = accA[j][3];
        const float b0 = accB[j][0], b1v = accB[j][1], b2v = accB[j][2], b3 = accB[j][3];
        mm[o] = make_float2(fmaxf(fmaxf(a0, a1), fmaxf(a2, a3)),
                            fminf(fminf(a0, a1), fminf(a2, a3)));
        mm[o + WP] = make_float2(fmaxf(fmaxf(b0, b1v), fmaxf(b2v, b3)),
                                 fminf(fminf(b0, b1v), fminf(b2v, b3)));
        float s = a0 + a1 + a2 + a3 + b0 + b1v + b2v + b3;
        float q = a0 * a0 + a1 * a1 + a2 * a2 + a3 * a3
                + b0 * b0 + b1v * b1v + b2v * b2v + b3 * b3;
#pragma unroll
        for (int off = 32; off > 0; off >>= 1) {
            s += __shfl_xor(s, off);
            q += __shfl_xor(q, off);
        }
        if ((tid & 63) == 0) { red[tid >> 6][j] = s; redq[tid >> 6][j] = q; }
    }
    __syncthreads();
    if (tid < 8) {
        atomicAdd(&s_sum[c0 + tid],
                  red[0][tid] + red[1][tid] + red[2][tid] + red[3][tid]);
    } else if (tid < 16) {
        const int j = tid - 8;
        atomicAdd(&s_sq[c0 + j],
                  redq[0][j] + redq[1][j] + redq[2][j] + redq[3][j]);
    }
}

__global__ __launch_bounds__(256) void conv2_k(
    const float2* __restrict__ mm,
    const float* __restrict__ s1sum, const float* __restrict__ s1sq,
    const float* __restrict__ g1, const float* __restrict__ be1,
    const float* __restrict__ w2, const float* __restrict__ b2,
    float* __restrict__ y2,
    float* __restrict__ s_sum, float* __restrict__ s_sq)
{
    __shared__ float red[4][8], redq[4][8];
    const int tid = threadIdx.x;
    const int t = blockIdx.x * 256 + tid;   // 0..100351
    const int c0 = blockIdx.y * 8;
    const int n = t / 784;
    const int p = t % 784;
    const int oh = p / W2, ow = p % W2;
    const bool topok = oh > 0;
    const bool owok  = ow > 0;
    const float inv1 = 1.0f / (float)(BATCH * 112 * 112);

    float acc[8];
#pragma unroll
    for (int c = 0; c < 8; ++c) acc[c] = b2[c0 + c];

#pragma unroll 2
    for (int ci = 0; ci < C1; ++ci) {
        const float mean = s1sum[ci] * inv1;
        const float var  = s1sq[ci] * inv1 - mean * mean;
        const float s1 = g1[ci] * rsqrtf(var + 1e-5f);
        const float t1 = be1[ci] - mean * s1;

        const float2* pl = mm + (n * C1 + ci) * (HP * WP);
        float v[3][3];
#pragma unroll
        for (int kh = 0; kh < 3; ++kh) {
            const int ih = max(2 * oh - 1 + kh, 0);
            const float2* rowp = pl + ih * WP;
            const float4 f4 = *(const float4*)(rowp + 2 * ow);
            const float2 lp = rowp[max(2 * ow - 1, 0)];
            const bool rok = (kh > 0) || topok;   // folds for kh>0
            const float h0 = fmaxf(0.0f, fmaxf(s1 * lp.x + t1, s1 * lp.y + t1));
            const float h1 = fmaxf(0.0f, fmaxf(s1 * f4.x + t1, s1 * f4.y + t1));
            const float h2 = fmaxf(0.0f, fmaxf(s1 * f4.z + t1, s1 * f4.w + t1));
            v[kh][0] = (rok && owok) ? h0 : 0.0f;
            v[kh][1] = rok ? h1 : 0.0f;
            v[kh][2] = rok ? h2 : 0.0f;
        }
#pragma unroll
        for (int c = 0; c < 8; ++c) {
            const float* wc = w2 + ((c0 + c) * C1 + ci) * 9;   // uniform
            float a = acc[c];
            a += wc[0] * v[0][0]; a += wc[1] * v[0][1]; a += wc[2] * v[0][2];
            a += wc[3] * v[1][0]; a += wc[4] * v[1][1]; a += wc[5] * v[1][2];
            a += wc[6] * v[2][0]; a += wc[7] * v[2][1]; a += wc[8] * v[2][2];
            acc[c] = a;
        }
    }

#pragma unroll
    for (int c = 0; c < 8; ++c) {
        const float a = acc[c];
        y2[(n * C2 + c0 + c) * (H2 * W2) + p] = a;
        float s = a, q = a * a;
#pragma unroll
        for (int off = 32; off > 0; off >>= 1) {
            s += __shfl_xor(s, off);
            q += __shfl_xor(q, off);
        }
        if ((tid & 63) == 0) { red[tid >> 6][c] = s; redq[tid >> 6][c] = q; }
    }
    __syncthreads();
    if (tid < 8) {
        atomicAdd(&s_sum[c0 + tid],
                  red[0][tid] + red[1][tid] + red[2][tid] + red[3][tid]);
    } else if (tid < 16) {
        const int c = tid - 8;
        atomicAdd(&s_sq[c0 + c],
                  redq[0][c] + redq[1][c] + redq[2][c] + redq[3][c]);
    }
}

__global__ __launch_bounds__(256) void head_fused_k(
    const float* __restrict__ y2,
    const float* __restrict__ s2sum, const float* __restrict__ s2sq,
    const float* __restrict__ g2, const float* __restrict__ be2,
    const float* __restrict__ fcw, const float* __restrict__ fcb,
    float* __restrict__ out)
{
    __shared__ float feat[C2];
    const int n = blockIdx.x;
    const int tid = threadIdx.x;
    const int wave = tid >> 6, lane = tid & 63;
    const float inv2 = 1.0f / (float)(BATCH * H2 * W2);
#pragma unroll
    for (int k = 0; k < 8; ++k) {
        const int c = wave * 8 + k;
        const float mean = s2sum[c] * inv2;
        const float var  = s2sq[c] * inv2 - mean * mean;
        const float s = g2[c] * rsqrtf(var + 1e-5f);
        const float t = be2[c] - mean * s;
        const float4* yp = (const float4*)(y2 + (n * C2 + c) * (H2 * W2));
        float a = 0.0f;
        for (int i = lane; i < 196; i += 64) {       // 196 quads = 784
            const float4 v = yp[i];
            a += fmaxf(0.0f, s * v.x + t) + fmaxf(0.0f, s * v.y + t)
               + fmaxf(0.0f, s * v.z + t) + fmaxf(0.0f, s * v.w + t);
        }
#pragma unroll
        for (int off = 32; off > 0; off >>= 1) a += __shfl_xor(a, off);
        if (lane == 0) feat[c] = a * (1.0f / (H2 * W2));
    }
    __syncthreads();
    if (tid == 0) {
        float logit = fcb[0];
#pragma unroll
        for (int c = 0; c < C2; ++c) logit += feat[c] * fcw[c];
        const float pc = cosf(logit);
        out[2 * n]     = pc;
        out[2 * n + 1] = 1.0f - pc;
    }
}

extern "C" void kernel_launch(void* const* d_in, const int* in_sizes, int n_in,
                              void* d_out, int out_size, void* d_ws, size_t ws_size,
                              hipStream_t stream) {
    const float* x   = (const float*)d_in[0];
    const float* w1  = (const float*)d_in[1];
    const float* b1  = (const float*)d_in[2];
    const float* g1  = (const float*)d_in[3];
    const float* be1 = (const float*)d_in[4];
    const float* w2  = (const float*)d_in[5];
    const float* b2  = (const float*)d_in[6];
    const float* g2  = (const float*)d_in[7];
    const float* be2 = (const float*)d_in[8];
    const float* fcw = (const float*)d_in[9];
    const float* fcb = (const float*)d_in[10];
    float* out = (float*)d_out;

    float* ws = (float*)d_ws;
    float2* mm = (float2*)ws;                              // 6,422,528 float2
    float* y2 = ws + (size_t)2 * BATCH * C1 * HP * WP;     // 3,211,264 floats
    float* stats = y2 + (size_t)BATCH * C2 * H2 * W2;
    float* s1sum = stats;          // 16
    float* s1sq  = stats + 16;     // 16
    float* s2sum = stats + 32;     // 32
    float* s2sq  = stats + 64;     // 32
    // ws use ~64.3 MB (proven safe)

    hipMemsetAsync(stats, 0, 96 * sizeof(float), stream);

    conv1_fused_k<<<dim3(784, 2), 256, 0, stream>>>(x, w1, b1, mm, s1sum, s1sq);
    conv2_k<<<dim3(392, 4), 256, 0, stream>>>(mm, s1sum, s1sq, g1, be1,
                                              w2, b2, y2, s2sum, s2sq);
    head_fused_k<<<BATCH, 256, 0, stream>>>(y2, s2sum, s2sq, g2, be2,
                                            fcw, fcb, out);
}